// Round 9
// baseline (351.936 us; speedup 1.0000x reference)
//
#include <hip/hip_runtime.h>

typedef float f32x4 __attribute__((ext_vector_type(4)));
typedef short s16x8 __attribute__((ext_vector_type(8)));
typedef unsigned short u16;

__device__ __forceinline__ u16 f2bf(float f) {
    union { float f; unsigned u; } v; v.f = f;
    return (u16)((v.u + 0x7fffu + ((v.u >> 16) & 1u)) >> 16);
}
__device__ __forceinline__ float bf2f(u16 h) {
    union { unsigned u; float f; } v; v.u = ((unsigned)h) << 16;
    return v.f;
}
__device__ __forceinline__ float fast_exp2(float x) {
#if __has_builtin(__builtin_amdgcn_exp2f)
    return __builtin_amdgcn_exp2f(x);
#else
    return exp2f(x);
#endif
}

// async global->LDS, 16B/lane; LDS dest = wave-uniform base + lane*16 [m97/m104]
__device__ __forceinline__ void gload_lds16(const void* g, void* l) {
    __builtin_amdgcn_global_load_lds((__attribute__((address_space(1))) void*)g,
                                     (__attribute__((address_space(3))) void*)l, 16, 0, 0);
}

// Mega convert: x (1048576 units) -> xb, then wq|wk|wv (524288+131072+131072) -> wqkvb
// contiguous. 1 unit = 8 elems. Grid exactly 7168 blocks x 256.
__global__ __launch_bounds__(256) void cvt_all(const float* __restrict__ x,  const float* __restrict__ wq,
                                               const float* __restrict__ wk, const float* __restrict__ wv,
                                               u16* __restrict__ xb, u16* __restrict__ wqkvb) {
    int u = blockIdx.x * 256 + threadIdx.x;
    const float* src;
    u16* dst;
    if (u < 1048576) { src = x + (size_t)u * 8; dst = xb + (size_t)u * 8; }
    else {
        int w = u - 1048576;
        dst = wqkvb + (size_t)w * 8;
        if (w < 524288)      src = wq + (size_t)w * 8;
        else if (w < 655360) src = wk + (size_t)(w - 524288) * 8;
        else                 src = wv + (size_t)(w - 655360) * 8;
    }
    const float4* p = (const float4*)src;
    float4 a = p[0], b = p[1];
    s16x8 o;
    o[0] = f2bf(a.x); o[1] = f2bf(a.y); o[2] = f2bf(a.z); o[3] = f2bf(a.w);
    o[4] = f2bf(b.x); o[5] = f2bf(b.y); o[6] = f2bf(b.z); o[7] = f2bf(b.w);
    *(s16x8*)dst = o;
}

// fp32 -> bf16 elementwise (for wo after wqkv region is free)
__global__ __launch_bounds__(256) void cvt_kernel(const float* __restrict__ in,
                                                  u16* __restrict__ out, int n8) {
    int i = blockIdx.x * 256 + threadIdx.x;
    if (i >= n8) return;
    const float4* p = (const float4*)(in + (size_t)i * 8);
    float4 a = p[0], b = p[1];
    s16x8 o;
    o[0] = f2bf(a.x); o[1] = f2bf(a.y); o[2] = f2bf(a.z); o[3] = f2bf(a.w);
    o[4] = f2bf(b.x); o[5] = f2bf(b.y); o[6] = f2bf(b.z); o[7] = f2bf(b.w);
    *(s16x8*)(out + (size_t)i * 8) = o;
}

// combine split halves for super-tiles qs in [32,64): ab = (O0+O1)/(L0+L1).
// Opart layout: [pi][32 rows][512 cols] f32, pi = (hsel*8+g)*32 + (qs-32).
// i indexes (g, qsi, row32, colblk): 8*32*32*64 = 524288 threads.
__global__ __launch_bounds__(256) void norm_comb(const float* __restrict__ Opart,
                                                 const float* __restrict__ Lpart,
                                                 u16* __restrict__ ab) {
    int i = blockIdx.x * 256 + threadIdx.x;
    int c0 = (i & 63) * 8;
    int r2 = i >> 6;
    int row32 = r2 & 31;
    int r3 = r2 >> 5;
    int qsi = r3 & 31;
    int g = r3 >> 5;                        // 0..7
    int head = c0 >> 7;                     // head within group
    size_t pi0 = (size_t)(g * 32 + qsi);
    size_t pi1 = (size_t)((8 + g) * 32 + qsi);
    const float* p0 = Opart + pi0 * 16384 + row32 * 512 + c0;
    const float* p1 = Opart + pi1 * 16384 + row32 * 512 + c0;
    float L0 = Lpart[pi0 * 128 + row32 * 4 + head];
    float L1 = Lpart[pi1 * 128 + row32 * 4 + head];
    float inv = 1.0f / (L0 + L1);
    int b = g >> 2, kv = g & 3;
    int token = (32 + qsi) * 32 + row32;    // rows 1024..2047
    u16* pd = ab + ((size_t)(b * 2048 + token) << 11) + kv * 512 + c0;
    float4 a0 = ((const float4*)p0)[0], a1 = ((const float4*)p0)[1];
    float4 b0 = ((const float4*)p1)[0], b1 = ((const float4*)p1)[1];
    s16x8 o;
    o[0] = f2bf((a0.x + b0.x) * inv); o[1] = f2bf((a0.y + b0.y) * inv);
    o[2] = f2bf((a0.z + b0.z) * inv); o[3] = f2bf((a0.w + b0.w) * inv);
    o[4] = f2bf((a1.x + b1.x) * inv); o[5] = f2bf((a1.y + b1.y) * inv);
    o[6] = f2bf((a1.z + b1.z) * inv); o[7] = f2bf((a1.w + b1.w) * inv);
    *(s16x8*)pd = o;
}

// C = A[M,K] @ B[N,K]^T, bf16 in. 128x128 tile, BK=64, global_load_lds staging,
// XOR-swizzled LDS. OUT=1: fp32 C[M,N]. OUT=4: fused qkv routing:
//   n<2048 -> bf16 Cq[m*2048+n]; 2048<=n<2560 -> bf16 Ck[m*512+(n-2048)];
//   n>=2560 -> bf16 transposed Cv[(n-2560)*M + m]
template<int OUT>
__global__ __launch_bounds__(256) void gemm128(const u16* __restrict__ A, const u16* __restrict__ B,
                                               void* __restrict__ C, void* __restrict__ Ck,
                                               void* __restrict__ Cv, int M, int N, int K) {
    __shared__ __align__(16) u16 Ald[128 * 64];
    __shared__ __align__(16) u16 Bld[128 * 64];
    const int t = threadIdx.x, wid = t >> 6, lane = t & 63;
    const int m0 = blockIdx.y * 128, n0 = blockIdx.x * 128;
    const int ml = lane & 15, quad = lane >> 4, m7 = ml & 7;
    const int wm = (wid & 1) * 64, wn = (wid >> 1) * 64;
    const int sr = lane >> 3, sc = lane & 7;

    f32x4 acc[4][4] = {};

    for (int k0 = 0; k0 < K; k0 += 64) {
        if (k0) __syncthreads();
        #pragma unroll
        for (int i = 0; i < 4; ++i) {
            int seg = wid * 4 + i;
            int r = seg * 8 + sr;
            int c = (sc ^ (r & 7)) * 8;
            gload_lds16(A + (size_t)(m0 + r) * K + k0 + c, &Ald[seg * 512]);
            gload_lds16(B + (size_t)(n0 + r) * K + k0 + c, &Bld[seg * 512]);
        }
        __syncthreads();
        #pragma unroll
        for (int kk = 0; kk < 64; kk += 32) {
            s16x8 af[4], bf[4];
            #pragma unroll
            for (int mi = 0; mi < 4; ++mi)
                af[mi] = *(const s16x8*)&Ald[(wm + mi * 16 + ml) * 64 + (((kk >> 3) + quad) ^ m7) * 8];
            #pragma unroll
            for (int ni = 0; ni < 4; ++ni)
                bf[ni] = *(const s16x8*)&Bld[(wn + ni * 16 + ml) * 64 + (((kk >> 3) + quad) ^ m7) * 8];
            #pragma unroll
            for (int mi = 0; mi < 4; ++mi)
                #pragma unroll
                for (int ni = 0; ni < 4; ++ni)
                    acc[mi][ni] = __builtin_amdgcn_mfma_f32_16x16x32_bf16(af[mi], bf[ni], acc[mi][ni], 0, 0, 0);
        }
    }
    // C/D layout: col=lane&15, row=quad*4+reg [m89/m91]
    #pragma unroll
    for (int mi = 0; mi < 4; ++mi)
        #pragma unroll
        for (int ni = 0; ni < 4; ++ni) {
            int gmb = m0 + wm + mi * 16 + quad * 4;
            int gn  = n0 + wn + ni * 16 + ml;
            if constexpr (OUT == 4) {
                if (n0 < 2048) {
                    #pragma unroll
                    for (int r = 0; r < 4; ++r)
                        ((u16*)C)[(size_t)(gmb + r) * 2048 + gn] = f2bf(acc[mi][ni][r]);
                } else if (n0 < 2560) {
                    #pragma unroll
                    for (int r = 0; r < 4; ++r)
                        ((u16*)Ck)[(size_t)(gmb + r) * 512 + (gn - 2048)] = f2bf(acc[mi][ni][r]);
                } else {
                    ushort4 v;
                    v.x = f2bf(acc[mi][ni][0]); v.y = f2bf(acc[mi][ni][1]);
                    v.z = f2bf(acc[mi][ni][2]); v.w = f2bf(acc[mi][ni][3]);
                    *(ushort4*)((u16*)Cv + (size_t)(gn - 2560) * M + gmb) = v;
                }
            } else {
                #pragma unroll
                for (int r = 0; r < 4; ++r)
                    ((float*)C)[(size_t)(gmb + r) * N + gn] = acc[mi][ni][r];
            }
        }
}

// Fused NeoX RoPE for q (16 heads, scaled) + k (4 heads). pos = tok % 2048.
// q pre-scaled by 1/sqrt(128)*log2(e) -> attention works in the log2 domain.
__global__ __launch_bounds__(256) void rope_kernel(u16* __restrict__ qb, u16* __restrict__ kb,
                                                   int nq, int ntot, float sq) {
    int idx = blockIdx.x * 256 + threadIdx.x;
    if (idx >= ntot) return;
    u16* base; int nheads; float scl; int id;
    if (idx < nq) { base = qb; nheads = 16; scl = sq;  id = idx; }
    else          { base = kb; nheads = 4;  scl = 1.f; id = idx - nq; }
    int i = id & 63;
    int rest = id >> 6;
    int hh = rest % nheads;
    int tok = rest / nheads;
    int tpos = tok & 2047;
    u16* row = base + (size_t)tok * nheads * 128 + hh * 128;
    float x1 = bf2f(row[i]);
    float x2 = bf2f(row[i + 64]);
    float inv = expf(-(float)i * 0.14391156731570787f); // 10000^(-i/64)
    float ang = (float)tpos * inv;
    float s, c;
    sincosf(ang, &s, &c);
    row[i]      = f2bf((x1 * c - x2 * s) * scl);
    row[i + 64] = f2bf((x2 * c + x1 * s) * scl);
}

// ---------- v3 attention (fallback when workspace too small) ----------
__global__ __launch_bounds__(256, 4) void attn_kernel(const u16* __restrict__ Q, const u16* __restrict__ Kb,
                                                      const u16* __restrict__ Vt, u16* __restrict__ O) {
    __shared__ __align__(16) u16 Klds[64 * 128];   // 16KB
    __shared__ __align__(16) u16 Vlds[128 * 64];   // 16KB
    __shared__ __align__(16) u16 Plds[4][16 * 64]; // 8KB
    const int t = threadIdx.x, wslot = t >> 6, lane = t & 63;
    const int kv = blockIdx.y, b = blockIdx.z;
    const int g = kv + 4 * b;
    const int bx = blockIdx.x;
    int qt;
    switch ((g >> 1) & 3) {
        case 0:  qt = bx; break;
        case 1:  qt = 127 - bx; break;
        case 2:  qt = (bx + 64) & 127; break;
        default: qt = (63 - bx) & 127; break;
    }
    const int h = kv * 4 + wslot;
    const int ml = lane & 15, quad = lane >> 4, m7 = ml & 7;
    const int t0 = qt * 16;
    const int n = (qt >> 2) + 1;

    s16x8 qf[4];
    {
        const u16* qp = Q + ((size_t)(b * 2048 + t0 + ml) * 2048 + h * 128);
        #pragma unroll
        for (int kc = 0; kc < 4; ++kc)
            qf[kc] = *(const s16x8*)(qp + kc * 32 + quad * 8);
    }

    s16x8 ones;
    #pragma unroll
    for (int j = 0; j < 8; ++j) ones[j] = (short)0x3F80;

    f32x4 Oa[8] = {};
    f32x4 L = {};

    for (int it = 0; it < n; ++it) {
        const int s0 = it * 64;
        if (it) __syncthreads();
        #pragma unroll
        for (int i = 0; i < 4; ++i) {
            int seg = wslot * 4 + i;
            int kr = seg * 4 + (lane >> 4);
            int kc = ((lane & 15) ^ (kr & 7)) * 8;
            gload_lds16(Kb + (size_t)(b * 2048 + s0 + kr) * 512 + kv * 128 + kc, &Klds[seg * 512]);
            int vr = seg * 8 + (lane >> 3);
            int vc = ((lane & 7) ^ (vr & 7)) * 8;
            gload_lds16(Vt + (size_t)(kv * 128 + vr) * 4096 + b * 2048 + s0 + vc, &Vlds[seg * 512]);
        }
        __syncthreads();

        f32x4 S[4] = {};
        #pragma unroll
        for (int kc = 0; kc < 4; ++kc)
            #pragma unroll
            for (int ti = 0; ti < 4; ++ti) {
                s16x8 kf = *(const s16x8*)&Klds[(ti * 16 + ml) * 128 + ((kc * 4 + quad) ^ m7) * 8];
                S[ti] = __builtin_amdgcn_mfma_f32_16x16x32_bf16(qf[kc], kf, S[ti], 0, 0, 0);
            }

        {
            u16* pl = &Plds[wslot][0];
            const bool diag = (it == n - 1);
            #pragma unroll
            for (int r = 0; r < 4; ++r) {
                int qr = t0 + quad * 4 + r;
                int row = quad * 4 + r;
                #pragma unroll
                for (int ti = 0; ti < 4; ++ti) {
                    float e = fast_exp2(S[ti][r]);
                    if (diag && (s0 + ti * 16 + ml > qr)) e = 0.f;
                    union { float f; unsigned u; } cv; cv.f = e;
                    pl[row * 64 + (((ti * 2 + (ml >> 3)) ^ (row & 7)) * 8) + (ml & 7)] = (u16)(cv.u >> 16);
                }
            }
        }
        asm volatile("s_waitcnt lgkmcnt(0)" ::: "memory");
        s16x8 pf[2];
        pf[0] = *(const s16x8*)&Plds[wslot][ml * 64 + ((quad)     ^ m7) * 8];
        pf[1] = *(const s16x8*)&Plds[wslot][ml * 64 + ((4 + quad) ^ m7) * 8];
        asm volatile("s_waitcnt lgkmcnt(0)" ::: "memory");

        #pragma unroll
        for (int c = 0; c < 2; ++c) {
            #pragma unroll
            for (int nt = 0; nt < 8; ++nt) {
                s16x8 vf = *(const s16x8*)&Vlds[(nt * 16 + ml) * 64 + ((c * 4 + quad) ^ m7) * 8];
                Oa[nt] = __builtin_amdgcn_mfma_f32_16x16x32_bf16(pf[c], vf, Oa[nt], 0, 0, 0);
            }
            L = __builtin_amdgcn_mfma_f32_16x16x32_bf16(pf[c], ones, L, 0, 0, 0);
        }
    }

    #pragma unroll
    for (int nt = 0; nt < 8; ++nt)
        #pragma unroll
        for (int r = 0; r < 4; ++r) {
            int col = h * 128 + nt * 16 + ml;
            O[(size_t)(b * 2048 + t0 + quad * 4 + r) * 2048 + col] = f2bf(Oa[nt][r] / L[r]);
        }
}

// ---------- v10 attention: pair-adjacent q-tiles in wave ----------
// Evidence chain: v9 measured wall = max_iters x contended_T_iter, where
// contended T_iter ~ n_resident x per-block-iter LDS cycles -> the LDS pipe is
// the shared bottleneck. v10 halves LDS cycles per unit work: each wave holds
// TWO adjacent 16-row q-tiles (rows 32qs..32qs+31); every kf/vf ds_read feeds
// 2 MFMAs (v0-validated structure, but adjacent tiles -> identical KV range, no
// wasted staging, no divergent branches). Iterations per super-tile n=(qs>>1)+1
// (1..32); qs>=32 KV-split into halves <=16 iters writing f32 partials with
// plain stores (v9 machinery) -- partial O (32MB exact) lives in d_out (final
// GEMM overwrites it afterward; stream-ordered), Lpart (256KB) in ws.
// 768 blocks longest-first. LDS 48KB, launch_bounds(256,3): 3 blocks/CU,
// VGPR cap ~168 (peak live ~144, no spill -- v5's failure was a 64-cap).
__global__ __launch_bounds__(256, 3) void attn_pair(const u16* __restrict__ Q, const u16* __restrict__ Kb,
                                                    const u16* __restrict__ Vt, u16* __restrict__ O,
                                                    float* __restrict__ Opart, float* __restrict__ Lpart) {
    __shared__ __align__(16) u16 Klds[64 * 128];       // 16KB
    __shared__ __align__(16) u16 Vlds[128 * 64];       // 16KB
    __shared__ __align__(16) u16 Plds[4][2][16 * 64];  // 16KB
    const int t = threadIdx.x, wslot = t >> 6, lane = t & 63;
    const int bid = blockIdx.x;          // 768 blocks
    const int g = bid & 7, idx = bid >> 3;   // g: group; idx: work unit, longest-first
    const int kv = g & 3, b = g >> 2;

    // idx 0..63: halves of qs 63..32 (len 8..16); idx 64..95: qs 31..0 (len 16..1)
    int qs, it0, it1, n, hsel = 0;
    bool partial;
    if (idx < 64) {
        int p = idx >> 1; hsel = idx & 1;
        qs = 63 - p; n = (qs >> 1) + 1;      // 17..32
        int nh = n >> 1;                     // 8..16
        it0 = hsel ? nh : 0;
        it1 = hsel ? n : nh;
        partial = true;
    } else {
        qs = 95 - idx; n = (qs >> 1) + 1;    // 1..16
        it0 = 0; it1 = n;
        partial = false;
    }

    const int h = kv * 4 + wslot;
    const int ml = lane & 15, quad = lane >> 4, m7 = ml & 7;
    const int t0a = qs * 32, t0b = qs * 32 + 16;

    // Q fragments for both tiles: A layout m=lane&15, k=quad*8+j [m120]
    s16x8 qfA[4], qfB[4];
    {
        const u16* qpA = Q + ((size_t)(b * 2048 + t0a + ml) * 2048 + h * 128);
        const u16* qpB = Q + ((size_t)(b * 2048 + t0b + ml) * 2048 + h * 128);
        #pragma unroll
        for (int kc = 0; kc < 4; ++kc) {
            qfA[kc] = *(const s16x8*)(qpA + kc * 32 + quad * 8);
            qfB[kc] = *(const s16x8*)(qpB + kc * 32 + quad * 8);
        }
    }

    s16x8 ones;
    #pragma unroll
    for (int j = 0; j < 8; ++j) ones[j] = (short)0x3F80; // bf16 1.0

    f32x4 OA[8] = {}, OB[8] = {};
    f32x4 LA = {}, LB = {};

    for (int it = it0; it < it1; ++it) {
        const int s0 = it * 64;
        if (it != it0) __syncthreads(); // all waves done reading previous K/V tile
        #pragma unroll
        for (int i = 0; i < 4; ++i) {
            int seg = wslot * 4 + i;
            int kr = seg * 4 + (lane >> 4);
            int kc = ((lane & 15) ^ (kr & 7)) * 8;
            gload_lds16(Kb + (size_t)(b * 2048 + s0 + kr) * 512 + kv * 128 + kc, &Klds[seg * 512]);
            int vr = seg * 8 + (lane >> 3);
            int vc = ((lane & 7) ^ (vr & 7)) * 8;
            gload_lds16(Vt + (size_t)(kv * 128 + vr) * 4096 + b * 2048 + s0 + vc, &Vlds[seg * 512]);
        }
        __syncthreads(); // staging drained (vmcnt0)

        // QK^T: each kf feeds BOTH tiles' MFMAs (the LDS-traffic halving)
        f32x4 Sa[4] = {}, Sb[4] = {};
        #pragma unroll
        for (int kc = 0; kc < 4; ++kc)
            #pragma unroll
            for (int ti = 0; ti < 4; ++ti) {
                s16x8 kf = *(const s16x8*)&Klds[(ti * 16 + ml) * 128 + ((kc * 4 + quad) ^ m7) * 8];
                Sa[ti] = __builtin_amdgcn_mfma_f32_16x16x32_bf16(qfA[kc], kf, Sa[ti], 0, 0, 0);
                Sb[ti] = __builtin_amdgcn_mfma_f32_16x16x32_bf16(qfB[kc], kf, Sb[ti], 0, 0, 0);
            }

        // softmax (no max-shift): p = exp2(s); mask only on the diagonal iter
        // (it == n-1; h0 halves end at nh-1 < n-1, never masked)
        const bool diag = (it == n - 1);
        auto do_soft = [&](f32x4* S, int t0, int pslot) {
            u16* pl = &Plds[wslot][pslot][0];
            #pragma unroll
            for (int r = 0; r < 4; ++r) {
                int qr = t0 + quad * 4 + r;
                int row = quad * 4 + r;
                #pragma unroll
                for (int ti = 0; ti < 4; ++ti) {
                    float e = fast_exp2(S[ti][r]);
                    if (diag && (s0 + ti * 16 + ml > qr)) e = 0.f;
                    union { float f; unsigned u; } cv; cv.f = e;
                    pl[row * 64 + (((ti * 2 + (ml >> 3)) ^ (row & 7)) * 8) + (ml & 7)] = (u16)(cv.u >> 16);
                }
            }
        };
        do_soft(Sa, t0a, 0);
        do_soft(Sb, t0b, 1);
        asm volatile("s_waitcnt lgkmcnt(0)" ::: "memory");
        s16x8 pfA[2], pfB[2];
        pfA[0] = *(const s16x8*)&Plds[wslot][0][ml * 64 + ((quad)     ^ m7) * 8];
        pfA[1] = *(const s16x8*)&Plds[wslot][0][ml * 64 + ((4 + quad) ^ m7) * 8];
        pfB[0] = *(const s16x8*)&Plds[wslot][1][ml * 64 + ((quad)     ^ m7) * 8];
        pfB[1] = *(const s16x8*)&Plds[wslot][1][ml * 64 + ((4 + quad) ^ m7) * 8];
        asm volatile("s_waitcnt lgkmcnt(0)" ::: "memory");

        // PV + l: each vf feeds both tiles
        #pragma unroll
        for (int c = 0; c < 2; ++c) {
            #pragma unroll
            for (int nt = 0; nt < 8; ++nt) {
                s16x8 vf = *(const s16x8*)&Vlds[(nt * 16 + ml) * 64 + ((c * 4 + quad) ^ m7) * 8];
                OA[nt] = __builtin_amdgcn_mfma_f32_16x16x32_bf16(pfA[c], vf, OA[nt], 0, 0, 0);
                OB[nt] = __builtin_amdgcn_mfma_f32_16x16x32_bf16(pfB[c], vf, OB[nt], 0, 0, 0);
            }
            LA = __builtin_amdgcn_mfma_f32_16x16x32_bf16(pfA[c], ones, LA, 0, 0, 0);
            LB = __builtin_amdgcn_mfma_f32_16x16x32_bf16(pfB[c], ones, LB, 0, 0, 0);
        }
    }

    if (!partial) {
        #pragma unroll
        for (int nt = 0; nt < 8; ++nt)
            #pragma unroll
            for (int r = 0; r < 4; ++r) {
                int col = h * 128 + nt * 16 + ml;
                O[(size_t)(b * 2048 + t0a + quad * 4 + r) * 2048 + col] = f2bf(OA[nt][r] / LA[r]);
                O[(size_t)(b * 2048 + t0b + quad * 4 + r) * 2048 + col] = f2bf(OB[nt][r] / LB[r]);
            }
    } else {
        // plain f32 partial stores (disjoint per half; full coverage -> no zeroing)
        const size_t pi = (size_t)((hsel * 8 + g) * 32 + (qs - 32));
        float* Ob = Opart + pi * 16384;
        float* Lb = Lpart + pi * 128;
        #pragma unroll
        for (int nt = 0; nt < 8; ++nt)
            #pragma unroll
            for (int r = 0; r < 4; ++r) {
                int c = wslot * 128 + nt * 16 + ml;
                Ob[(quad * 4 + r) * 512 + c]        = OA[nt][r];
                Ob[(16 + quad * 4 + r) * 512 + c]   = OB[nt][r];
            }
        if (ml == 0) {
            #pragma unroll
            for (int r = 0; r < 4; ++r) {
                Lb[(quad * 4 + r) * 4 + wslot]      = LA[r];
                Lb[(16 + quad * 4 + r) * 4 + wslot] = LB[r];
            }
        }
    }
}

extern "C" void kernel_launch(void* const* d_in, const int* in_sizes, int n_in,
                              void* d_out, int out_size, void* d_ws, size_t ws_size,
                              hipStream_t stream) {
    const float* x  = (const float*)d_in[0];
    const float* wq = (const float*)d_in[1];
    const float* wk = (const float*)d_in[2];
    const float* wv = (const float*)d_in[3];
    const float* wo = (const float*)d_in[4];
    float* out = (float*)d_out;
    char* ws = (char*)d_ws;

    const size_t MB = 1024 * 1024;
    // ws: [0,16M) xb (reused as ab) | [16M,32M) qb | [32M,36M) kb |
    //     [36M,40M) vtb | [40M,52M) wqkvb (reused as wob) | [52M,52.25M) Lpart
    // O-partials (32MB exact) live in d_out: final GEMM overwrites every byte.
    u16* xb    = (u16*)(ws);
    u16* qb    = (u16*)(ws + 16 * MB);
    u16* kb    = (u16*)(ws + 32 * MB);
    u16* vtb   = (u16*)(ws + 36 * MB);
    u16* wqkvb = (u16*)(ws + 40 * MB);
    u16* ab    = xb;    // attn output over xb (x last read by qkv GEMM)
    u16* wob   = wqkvb; // wo bf16 over wqkvb (last read by qkv GEMM)

    const bool split = ws_size >= 53 * MB; // r6 proved >=70MB available

    cvt_all<<<7168, 256, 0, stream>>>(x, wq, wk, wv, xb, wqkvb);

    gemm128<4><<<dim3(24, 32), 256, 0, stream>>>(xb, wqkvb, qb, kb, vtb, 4096, 3072, 2048);

    cvt_kernel<<<2048, 256, 0, stream>>>(wo, wob, 524288); // wqkvb region now free

    // q pre-scaled by 1/sqrt(128)*log2(e)
    rope_kernel<<<20480, 256, 0, stream>>>(qb, kb, 4194304, 5242880, 0.12751743f);

    if (split) {
        float* Opart = out;                    // 32MB scratch, overwritten by final GEMM
        float* Lpart = (float*)(ws + 52 * MB); // 256KB
        attn_pair<<<768, 256, 0, stream>>>(qb, kb, vtb, ab, Opart, Lpart);
        norm_comb<<<2048, 256, 0, stream>>>(Opart, Lpart, ab);
    } else {
        attn_kernel<<<dim3(128, 4, 2), 256, 0, stream>>>(qb, kb, vtb, ab);
    }

    gemm128<1><<<dim3(16, 32), 256, 0, stream>>>(ab, wob, out, nullptr, nullptr, 4096, 2048, 2048);
}

// Round 10
// 315.963 us; speedup vs baseline: 1.1139x; 1.1139x over previous
//
#include <hip/hip_runtime.h>

typedef float f32x4 __attribute__((ext_vector_type(4)));
typedef short s16x8 __attribute__((ext_vector_type(8)));
typedef unsigned short u16;

__device__ __forceinline__ u16 f2bf(float f) {
    union { float f; unsigned u; } v; v.f = f;
    return (u16)((v.u + 0x7fffu + ((v.u >> 16) & 1u)) >> 16);
}
__device__ __forceinline__ float bf2f(u16 h) {
    union { unsigned u; float f; } v; v.u = ((unsigned)h) << 16;
    return v.f;
}
__device__ __forceinline__ float fast_exp2(float x) {
#if __has_builtin(__builtin_amdgcn_exp2f)
    return __builtin_amdgcn_exp2f(x);
#else
    return exp2f(x);
#endif
}

// async global->LDS, 16B/lane; LDS dest = wave-uniform base + lane*16 [m97/m104]
__device__ __forceinline__ void gload_lds16(const void* g, void* l) {
    __builtin_amdgcn_global_load_lds((__attribute__((address_space(1))) void*)g,
                                     (__attribute__((address_space(3))) void*)l, 16, 0, 0);
}

// Mega convert: x (1048576 units) -> xb, then wq|wk|wv (524288+131072+131072) -> wqkvb
// contiguous. 1 unit = 8 elems. Grid exactly 7168 blocks x 256.
__global__ __launch_bounds__(256) void cvt_all(const float* __restrict__ x,  const float* __restrict__ wq,
                                               const float* __restrict__ wk, const float* __restrict__ wv,
                                               u16* __restrict__ xb, u16* __restrict__ wqkvb) {
    int u = blockIdx.x * 256 + threadIdx.x;
    const float* src;
    u16* dst;
    if (u < 1048576) { src = x + (size_t)u * 8; dst = xb + (size_t)u * 8; }
    else {
        int w = u - 1048576;
        dst = wqkvb + (size_t)w * 8;
        if (w < 524288)      src = wq + (size_t)w * 8;
        else if (w < 655360) src = wk + (size_t)(w - 524288) * 8;
        else                 src = wv + (size_t)(w - 655360) * 8;
    }
    const float4* p = (const float4*)src;
    float4 a = p[0], b = p[1];
    s16x8 o;
    o[0] = f2bf(a.x); o[1] = f2bf(a.y); o[2] = f2bf(a.z); o[3] = f2bf(a.w);
    o[4] = f2bf(b.x); o[5] = f2bf(b.y); o[6] = f2bf(b.z); o[7] = f2bf(b.w);
    *(s16x8*)dst = o;
}

// fp32 -> bf16 elementwise (for wo after wqkv region is free)
__global__ __launch_bounds__(256) void cvt_kernel(const float* __restrict__ in,
                                                  u16* __restrict__ out, int n8) {
    int i = blockIdx.x * 256 + threadIdx.x;
    if (i >= n8) return;
    const float4* p = (const float4*)(in + (size_t)i * 8);
    float4 a = p[0], b = p[1];
    s16x8 o;
    o[0] = f2bf(a.x); o[1] = f2bf(a.y); o[2] = f2bf(a.z); o[3] = f2bf(a.w);
    o[4] = f2bf(b.x); o[5] = f2bf(b.y); o[6] = f2bf(b.z); o[7] = f2bf(b.w);
    *(s16x8*)(out + (size_t)i * 8) = o;
}

// combine split halves for q-tiles qt in [64,128): ab = (O0+O1)/(L0+L1).
// Opart layout: [pi][16 rows][512 cols] f32, pi = (hsel*8+g)*64 + (qt-64).
// Lpart: [pi][row*4+head] f32.
// i indexes (g, qti, row, colblk): 8*64*16*64 = 524288 threads.
__global__ __launch_bounds__(256) void norm_comb(const float* __restrict__ Opart,
                                                 const float* __restrict__ Lpart,
                                                 u16* __restrict__ ab) {
    int i = blockIdx.x * 256 + threadIdx.x;
    int c0 = (i & 63) * 8;
    int r = i >> 6;
    int row = r & 15;
    int r2 = r >> 4;
    int qti = r2 & 63;
    int g = r2 >> 6;                        // 0..7
    int head = c0 >> 7;                     // head within group
    size_t pi0 = (size_t)(g * 64 + qti);
    size_t pi1 = (size_t)((8 + g) * 64 + qti);
    const float* p0 = Opart + pi0 * 8192 + row * 512 + c0;
    const float* p1 = Opart + pi1 * 8192 + row * 512 + c0;
    float L0 = Lpart[pi0 * 64 + row * 4 + head];
    float L1 = Lpart[pi1 * 64 + row * 4 + head];
    float inv = 1.0f / (L0 + L1);
    int b = g >> 2, kv = g & 3;
    int token = (64 + qti) * 16 + row;      // rows 1024..2047
    u16* pd = ab + ((size_t)(b * 2048 + token) << 11) + kv * 512 + c0;
    float4 a0 = ((const float4*)p0)[0], a1 = ((const float4*)p0)[1];
    float4 b0 = ((const float4*)p1)[0], b1 = ((const float4*)p1)[1];
    s16x8 o;
    o[0] = f2bf((a0.x + b0.x) * inv); o[1] = f2bf((a0.y + b0.y) * inv);
    o[2] = f2bf((a0.z + b0.z) * inv); o[3] = f2bf((a0.w + b0.w) * inv);
    o[4] = f2bf((a1.x + b1.x) * inv); o[5] = f2bf((a1.y + b1.y) * inv);
    o[6] = f2bf((a1.z + b1.z) * inv); o[7] = f2bf((a1.w + b1.w) * inv);
    *(s16x8*)pd = o;
}

// C = A[M,K] @ B[N,K]^T, bf16 in. 128x128 tile, BK=64, global_load_lds staging,
// XOR-swizzled LDS. OUT=1: fp32 C[M,N]. OUT=4: fused qkv routing:
//   n<2048 -> bf16 Cq[m*2048+n]; 2048<=n<2560 -> bf16 Ck[m*512+(n-2048)];
//   n>=2560 -> bf16 transposed Cv[(n-2560)*M + m]
template<int OUT>
__global__ __launch_bounds__(256) void gemm128(const u16* __restrict__ A, const u16* __restrict__ B,
                                               void* __restrict__ C, void* __restrict__ Ck,
                                               void* __restrict__ Cv, int M, int N, int K) {
    __shared__ __align__(16) u16 Ald[128 * 64];
    __shared__ __align__(16) u16 Bld[128 * 64];
    const int t = threadIdx.x, wid = t >> 6, lane = t & 63;
    const int m0 = blockIdx.y * 128, n0 = blockIdx.x * 128;
    const int ml = lane & 15, quad = lane >> 4, m7 = ml & 7;
    const int wm = (wid & 1) * 64, wn = (wid >> 1) * 64;
    const int sr = lane >> 3, sc = lane & 7;

    f32x4 acc[4][4] = {};

    for (int k0 = 0; k0 < K; k0 += 64) {
        if (k0) __syncthreads();
        #pragma unroll
        for (int i = 0; i < 4; ++i) {
            int seg = wid * 4 + i;
            int r = seg * 8 + sr;
            int c = (sc ^ (r & 7)) * 8;
            gload_lds16(A + (size_t)(m0 + r) * K + k0 + c, &Ald[seg * 512]);
            gload_lds16(B + (size_t)(n0 + r) * K + k0 + c, &Bld[seg * 512]);
        }
        __syncthreads();
        #pragma unroll
        for (int kk = 0; kk < 64; kk += 32) {
            s16x8 af[4], bf[4];
            #pragma unroll
            for (int mi = 0; mi < 4; ++mi)
                af[mi] = *(const s16x8*)&Ald[(wm + mi * 16 + ml) * 64 + (((kk >> 3) + quad) ^ m7) * 8];
            #pragma unroll
            for (int ni = 0; ni < 4; ++ni)
                bf[ni] = *(const s16x8*)&Bld[(wn + ni * 16 + ml) * 64 + (((kk >> 3) + quad) ^ m7) * 8];
            #pragma unroll
            for (int mi = 0; mi < 4; ++mi)
                #pragma unroll
                for (int ni = 0; ni < 4; ++ni)
                    acc[mi][ni] = __builtin_amdgcn_mfma_f32_16x16x32_bf16(af[mi], bf[ni], acc[mi][ni], 0, 0, 0);
        }
    }
    // C/D layout: col=lane&15, row=quad*4+reg [m89/m91]
    #pragma unroll
    for (int mi = 0; mi < 4; ++mi)
        #pragma unroll
        for (int ni = 0; ni < 4; ++ni) {
            int gmb = m0 + wm + mi * 16 + quad * 4;
            int gn  = n0 + wn + ni * 16 + ml;
            if constexpr (OUT == 4) {
                if (n0 < 2048) {
                    #pragma unroll
                    for (int r = 0; r < 4; ++r)
                        ((u16*)C)[(size_t)(gmb + r) * 2048 + gn] = f2bf(acc[mi][ni][r]);
                } else if (n0 < 2560) {
                    #pragma unroll
                    for (int r = 0; r < 4; ++r)
                        ((u16*)Ck)[(size_t)(gmb + r) * 512 + (gn - 2048)] = f2bf(acc[mi][ni][r]);
                } else {
                    ushort4 v;
                    v.x = f2bf(acc[mi][ni][0]); v.y = f2bf(acc[mi][ni][1]);
                    v.z = f2bf(acc[mi][ni][2]); v.w = f2bf(acc[mi][ni][3]);
                    *(ushort4*)((u16*)Cv + (size_t)(gn - 2560) * M + gmb) = v;
                }
            } else {
                #pragma unroll
                for (int r = 0; r < 4; ++r)
                    ((float*)C)[(size_t)(gmb + r) * N + gn] = acc[mi][ni][r];
            }
        }
}

// Fused NeoX RoPE for q (16 heads, scaled) + k (4 heads). pos = tok % 2048.
// q pre-scaled by 1/sqrt(128)*log2(e) -> attention works in the log2 domain.
__global__ __launch_bounds__(256) void rope_kernel(u16* __restrict__ qb, u16* __restrict__ kb,
                                                   int nq, int ntot, float sq) {
    int idx = blockIdx.x * 256 + threadIdx.x;
    if (idx >= ntot) return;
    u16* base; int nheads; float scl; int id;
    if (idx < nq) { base = qb; nheads = 16; scl = sq;  id = idx; }
    else          { base = kb; nheads = 4;  scl = 1.f; id = idx - nq; }
    int i = id & 63;
    int rest = id >> 6;
    int hh = rest % nheads;
    int tok = rest / nheads;
    int tpos = tok & 2047;
    u16* row = base + (size_t)tok * nheads * 128 + hh * 128;
    float x1 = bf2f(row[i]);
    float x2 = bf2f(row[i + 64]);
    float inv = expf(-(float)i * 0.14391156731570787f); // 10000^(-i/64)
    float ang = (float)tpos * inv;
    float s, c;
    sincosf(ang, &s, &c);
    row[i]      = f2bf((x1 * c - x2 * s) * scl);
    row[i + 64] = f2bf((x2 * c + x1 * s) * scl);
}

// ---------- v3 attention (fallback when workspace too small) ----------
__global__ __launch_bounds__(256, 4) void attn_kernel(const u16* __restrict__ Q, const u16* __restrict__ Kb,
                                                      const u16* __restrict__ Vt, u16* __restrict__ O) {
    __shared__ __align__(16) u16 Klds[64 * 128];   // 16KB
    __shared__ __align__(16) u16 Vlds[128 * 64];   // 16KB
    __shared__ __align__(16) u16 Plds[4][16 * 64]; // 8KB
    const int t = threadIdx.x, wslot = t >> 6, lane = t & 63;
    const int kv = blockIdx.y, b = blockIdx.z;
    const int g = kv + 4 * b;
    const int bx = blockIdx.x;
    int qt;
    switch ((g >> 1) & 3) {
        case 0:  qt = bx; break;
        case 1:  qt = 127 - bx; break;
        case 2:  qt = (bx + 64) & 127; break;
        default: qt = (63 - bx) & 127; break;
    }
    const int h = kv * 4 + wslot;
    const int ml = lane & 15, quad = lane >> 4, m7 = ml & 7;
    const int t0 = qt * 16;
    const int n = (qt >> 2) + 1;

    s16x8 qf[4];
    {
        const u16* qp = Q + ((size_t)(b * 2048 + t0 + ml) * 2048 + h * 128);
        #pragma unroll
        for (int kc = 0; kc < 4; ++kc)
            qf[kc] = *(const s16x8*)(qp + kc * 32 + quad * 8);
    }

    s16x8 ones;
    #pragma unroll
    for (int j = 0; j < 8; ++j) ones[j] = (short)0x3F80;

    f32x4 Oa[8] = {};
    f32x4 L = {};

    for (int it = 0; it < n; ++it) {
        const int s0 = it * 64;
        if (it) __syncthreads();
        #pragma unroll
        for (int i = 0; i < 4; ++i) {
            int seg = wslot * 4 + i;
            int kr = seg * 4 + (lane >> 4);
            int kc = ((lane & 15) ^ (kr & 7)) * 8;
            gload_lds16(Kb + (size_t)(b * 2048 + s0 + kr) * 512 + kv * 128 + kc, &Klds[seg * 512]);
            int vr = seg * 8 + (lane >> 3);
            int vc = ((lane & 7) ^ (vr & 7)) * 8;
            gload_lds16(Vt + (size_t)(kv * 128 + vr) * 4096 + b * 2048 + s0 + vc, &Vlds[seg * 512]);
        }
        __syncthreads();

        f32x4 S[4] = {};
        #pragma unroll
        for (int kc = 0; kc < 4; ++kc)
            #pragma unroll
            for (int ti = 0; ti < 4; ++ti) {
                s16x8 kf = *(const s16x8*)&Klds[(ti * 16 + ml) * 128 + ((kc * 4 + quad) ^ m7) * 8];
                S[ti] = __builtin_amdgcn_mfma_f32_16x16x32_bf16(qf[kc], kf, S[ti], 0, 0, 0);
            }

        {
            u16* pl = &Plds[wslot][0];
            const bool diag = (it == n - 1);
            #pragma unroll
            for (int r = 0; r < 4; ++r) {
                int qr = t0 + quad * 4 + r;
                int row = quad * 4 + r;
                #pragma unroll
                for (int ti = 0; ti < 4; ++ti) {
                    float e = fast_exp2(S[ti][r]);
                    if (diag && (s0 + ti * 16 + ml > qr)) e = 0.f;
                    union { float f; unsigned u; } cv; cv.f = e;
                    pl[row * 64 + (((ti * 2 + (ml >> 3)) ^ (row & 7)) * 8) + (ml & 7)] = (u16)(cv.u >> 16);
                }
            }
        }
        asm volatile("s_waitcnt lgkmcnt(0)" ::: "memory");
        s16x8 pf[2];
        pf[0] = *(const s16x8*)&Plds[wslot][ml * 64 + ((quad)     ^ m7) * 8];
        pf[1] = *(const s16x8*)&Plds[wslot][ml * 64 + ((4 + quad) ^ m7) * 8];
        asm volatile("s_waitcnt lgkmcnt(0)" ::: "memory");

        #pragma unroll
        for (int c = 0; c < 2; ++c) {
            #pragma unroll
            for (int nt = 0; nt < 8; ++nt) {
                s16x8 vf = *(const s16x8*)&Vlds[(nt * 16 + ml) * 64 + ((c * 4 + quad) ^ m7) * 8];
                Oa[nt] = __builtin_amdgcn_mfma_f32_16x16x32_bf16(pf[c], vf, Oa[nt], 0, 0, 0);
            }
            L = __builtin_amdgcn_mfma_f32_16x16x32_bf16(pf[c], ones, L, 0, 0, 0);
        }
    }

    #pragma unroll
    for (int nt = 0; nt < 8; ++nt)
        #pragma unroll
        for (int r = 0; r < 4; ++r) {
            int col = h * 128 + nt * 16 + ml;
            O[(size_t)(b * 2048 + t0 + quad * 4 + r) * 2048 + col] = f2bf(Oa[nt][r] / L[r]);
        }
}

// ---------- v11 attention: v9 body, split extended to ALL qt>=64 ----------
// Evidence chain: v3 wall = 32 x 8.2K (longest block); v9 capped at 24 -> 100us
// (= 24 x contended ~10K); v10 taught that doubling the per-iter chain and
// dropping backlog regresses. v11 keeps the proven v9 iteration body (64 VGPR,
// 40KB LDS, 4 blocks/CU) and caps max block at 16 iters: every qt in [64,128)
// is two KV-halves writing disjoint f32 partials with PLAIN stores (no atomics,
// no zeroing); norm_comb computes (O0+O1)/(L0+L1). Partials = exactly 32MB ->
// live in d_out (final GEMM overwrites; stream-ordered; validated r9).
// 1536 blocks = 6/CU backlog (fixes v10's drain). Unsplit tiles (len 16..1)
// first, then halves (len ~16..8) descending.
__global__ __launch_bounds__(256, 4) void attn_sched(const u16* __restrict__ Q, const u16* __restrict__ Kb,
                                                     const u16* __restrict__ Vt, u16* __restrict__ O,
                                                     float* __restrict__ Opart, float* __restrict__ Lpart) {
    __shared__ __align__(16) u16 Klds[64 * 128];   // 16KB
    __shared__ __align__(16) u16 Vlds[128 * 64];   // 16KB
    __shared__ __align__(16) u16 Plds[4][16 * 64]; // 8KB
    const int t = threadIdx.x, wslot = t >> 6, lane = t & 63;
    const int bid = blockIdx.x;          // 1536 blocks
    const int idx = bid >> 3, g = bid & 7;
    const int kv = g & 3, b = g >> 2;

    // work list: idx 0..63 unsplit qt 63..0 (len 16..1);
    // idx 64..191: halves of qt 127..64 (len ~16..8).
    int qt, it0, it1, n, hsel = 0;
    bool partial;
    if (idx < 64) {
        qt = 63 - idx; n = (qt >> 2) + 1; it0 = 0; it1 = n; partial = false;
    } else {
        int p = (idx - 64) >> 1; hsel = (idx - 64) & 1;
        qt = 127 - p; n = (qt >> 2) + 1;     // 32..17
        int nh = n >> 1;                     // 16..8
        it0 = hsel ? nh : 0;
        it1 = hsel ? n : nh;
        partial = true;
    }

    const int h = kv * 4 + wslot;
    const int ml = lane & 15, quad = lane >> 4, m7 = ml & 7;
    const int t0 = qt * 16;

    // Q fragments: A layout m=lane&15, k=quad*8+j [m120]
    s16x8 qf[4];
    {
        const u16* qp = Q + ((size_t)(b * 2048 + t0 + ml) * 2048 + h * 128);
        #pragma unroll
        for (int kc = 0; kc < 4; ++kc)
            qf[kc] = *(const s16x8*)(qp + kc * 32 + quad * 8);
    }

    s16x8 ones;
    #pragma unroll
    for (int j = 0; j < 8; ++j) ones[j] = (short)0x3F80; // bf16 1.0

    f32x4 Oa[8] = {};
    f32x4 L = {};

    for (int it = it0; it < it1; ++it) {
        const int s0 = it * 64;
        if (it != it0) __syncthreads(); // all waves done reading previous K/V tile
        #pragma unroll
        for (int i = 0; i < 4; ++i) {
            int seg = wslot * 4 + i;
            int kr = seg * 4 + (lane >> 4);
            int kc = ((lane & 15) ^ (kr & 7)) * 8;
            gload_lds16(Kb + (size_t)(b * 2048 + s0 + kr) * 512 + kv * 128 + kc, &Klds[seg * 512]);
            int vr = seg * 8 + (lane >> 3);
            int vc = ((lane & 7) ^ (vr & 7)) * 8;
            gload_lds16(Vt + (size_t)(kv * 128 + vr) * 4096 + b * 2048 + s0 + vc, &Vlds[seg * 512]);
        }
        __syncthreads(); // staging drained (vmcnt0)

        // QK^T
        f32x4 S[4] = {};
        #pragma unroll
        for (int kc = 0; kc < 4; ++kc)
            #pragma unroll
            for (int ti = 0; ti < 4; ++ti) {
                s16x8 kf = *(const s16x8*)&Klds[(ti * 16 + ml) * 128 + ((kc * 4 + quad) ^ m7) * 8];
                S[ti] = __builtin_amdgcn_mfma_f32_16x16x32_bf16(qf[kc], kf, S[ti], 0, 0, 0);
            }

        // softmax (no max-shift): p = exp2(s); causal mask only on diagonal iter
        // (it == n-1; h0 halves end at nh-1 < n-1, never masked)
        {
            u16* pl = &Plds[wslot][0];
            const bool diag = (it == n - 1);
            #pragma unroll
            for (int r = 0; r < 4; ++r) {
                int qr = t0 + quad * 4 + r;
                int row = quad * 4 + r;
                #pragma unroll
                for (int ti = 0; ti < 4; ++ti) {
                    float e = fast_exp2(S[ti][r]);
                    if (diag && (s0 + ti * 16 + ml > qr)) e = 0.f;
                    union { float f; unsigned u; } cv; cv.f = e;
                    pl[row * 64 + (((ti * 2 + (ml >> 3)) ^ (row & 7)) * 8) + (ml & 7)] = (u16)(cv.u >> 16);
                }
            }
        }
        asm volatile("s_waitcnt lgkmcnt(0)" ::: "memory");
        s16x8 pf[2];
        pf[0] = *(const s16x8*)&Plds[wslot][ml * 64 + ((quad)     ^ m7) * 8];
        pf[1] = *(const s16x8*)&Plds[wslot][ml * 64 + ((4 + quad) ^ m7) * 8];
        asm volatile("s_waitcnt lgkmcnt(0)" ::: "memory");

        // PV + l
        #pragma unroll
        for (int c = 0; c < 2; ++c) {
            #pragma unroll
            for (int nt = 0; nt < 8; ++nt) {
                s16x8 vf = *(const s16x8*)&Vlds[(nt * 16 + ml) * 64 + ((c * 4 + quad) ^ m7) * 8];
                Oa[nt] = __builtin_amdgcn_mfma_f32_16x16x32_bf16(pf[c], vf, Oa[nt], 0, 0, 0);
            }
            L = __builtin_amdgcn_mfma_f32_16x16x32_bf16(pf[c], ones, L, 0, 0, 0);
        }
    }

    if (!partial) {
        #pragma unroll
        for (int nt = 0; nt < 8; ++nt)
            #pragma unroll
            for (int r = 0; r < 4; ++r) {
                int col = h * 128 + nt * 16 + ml;
                O[(size_t)(b * 2048 + t0 + quad * 4 + r) * 2048 + col] = f2bf(Oa[nt][r] / L[r]);
            }
    } else {
        // plain f32 partial stores (disjoint per half; full coverage -> no zeroing)
        const int qti = qt - 64;
        const size_t pi = (size_t)((hsel * 8 + g) * 64 + qti);
        float* Ob = Opart + pi * 8192;
        #pragma unroll
        for (int nt = 0; nt < 8; ++nt)
            #pragma unroll
            for (int r = 0; r < 4; ++r)
                Ob[(quad * 4 + r) * 512 + wslot * 128 + nt * 16 + ml] = Oa[nt][r];
        if (ml == 0) {
            float* Lb = Lpart + pi * 64;
            #pragma unroll
            for (int r = 0; r < 4; ++r)
                Lb[(quad * 4 + r) * 4 + wslot] = L[r];
        }
    }
}

extern "C" void kernel_launch(void* const* d_in, const int* in_sizes, int n_in,
                              void* d_out, int out_size, void* d_ws, size_t ws_size,
                              hipStream_t stream) {
    const float* x  = (const float*)d_in[0];
    const float* wq = (const float*)d_in[1];
    const float* wk = (const float*)d_in[2];
    const float* wv = (const float*)d_in[3];
    const float* wo = (const float*)d_in[4];
    float* out = (float*)d_out;
    char* ws = (char*)d_ws;

    const size_t MB = 1024 * 1024;
    // ws: [0,16M) xb (reused as ab) | [16M,32M) qb | [32M,36M) kb |
    //     [36M,40M) vtb | [40M,52M) wqkvb (reused as wob) | [52M,52.25M) Lpart
    // O-partials (32MB exact) live in d_out: final GEMM overwrites every byte.
    u16* xb    = (u16*)(ws);
    u16* qb    = (u16*)(ws + 16 * MB);
    u16* kb    = (u16*)(ws + 32 * MB);
    u16* vtb   = (u16*)(ws + 36 * MB);
    u16* wqkvb = (u16*)(ws + 40 * MB);
    u16* ab    = xb;    // attn output over xb (x last read by qkv GEMM)
    u16* wob   = wqkvb; // wo bf16 over wqkvb (last read by qkv GEMM)

    const bool split = ws_size >= 53 * MB; // r6 proved >=70MB available

    cvt_all<<<7168, 256, 0, stream>>>(x, wq, wk, wv, xb, wqkvb);

    gemm128<4><<<dim3(24, 32), 256, 0, stream>>>(xb, wqkvb, qb, kb, vtb, 4096, 3072, 2048);

    cvt_kernel<<<2048, 256, 0, stream>>>(wo, wob, 524288); // wqkvb region now free

    // q pre-scaled by 1/sqrt(128)*log2(e)
    rope_kernel<<<20480, 256, 0, stream>>>(qb, kb, 4194304, 5242880, 0.12751743f);

    if (split) {
        float* Opart = out;                    // 32MB scratch, overwritten by final GEMM
        float* Lpart = (float*)(ws + 52 * MB); // 256KB
        attn_sched<<<1536, 256, 0, stream>>>(qb, kb, vtb, ab, Opart, Lpart);
        norm_comb<<<2048, 256, 0, stream>>>(Opart, Lpart, ab);
    } else {
        attn_kernel<<<dim3(128, 4, 2), 256, 0, stream>>>(qb, kb, vtb, ab);
    }

    gemm128<1><<<dim3(16, 32), 256, 0, stream>>>(ab, wob, out, nullptr, nullptr, 4096, 2048, 2048);
}